// Round 1
// baseline (491.011 us; speedup 1.0000x reference)
//
#include <hip/hip_runtime.h>

// Problem constants (from setup_inputs)
#define ND0 90112
#define ND1 8192
#define NE0 1351680
#define NE1 81920
#define F_IN 128
#define HID 256
#define F_OUT 128

// ------------------------------------------------------------------
// CSR build: histogram -> exclusive scan (two-level) -> scatter
// ------------------------------------------------------------------
__global__ void hist_k(const int* __restrict__ dst, int* __restrict__ cnt, int E) {
    int e = blockIdx.x * 256 + threadIdx.x;
    if (e < E) atomicAdd(&cnt[dst[e]], 1);
}

// chunk = 1024 elems per block; writes per-chunk exclusive scan + chunk total
__global__ void scan_part_k(const int* __restrict__ in, int* __restrict__ out,
                            int* __restrict__ bsum, int n) {
    __shared__ int sh[256];
    int base = blockIdx.x * 1024;
    int t = threadIdx.x;
    int v[4];
    int s = 0;
#pragma unroll
    for (int i = 0; i < 4; ++i) {
        int idx = base + t * 4 + i;
        v[i] = (idx < n) ? in[idx] : 0;
        s += v[i];
    }
    sh[t] = s;
    __syncthreads();
    for (int off = 1; off < 256; off <<= 1) {
        int x = (t >= off) ? sh[t - off] : 0;
        __syncthreads();
        sh[t] += x;
        __syncthreads();
    }
    int excl = (t == 0) ? 0 : sh[t - 1];
    if (t == 255 && bsum) bsum[blockIdx.x] = sh[255];
#pragma unroll
    for (int i = 0; i < 4; ++i) {
        int idx = base + t * 4 + i;
        if (idx < n) out[idx] = excl;
        excl += v[i];
    }
}

__global__ void scan_add_k(int* __restrict__ out, const int* __restrict__ boff, int n) {
    int i = blockIdx.x * 256 + threadIdx.x;
    if (i < n) out[i] += boff[i >> 10];
}

// scatter edges into CSR slots; optionally map src through n_id so the
// aggregation loop has a single indirection.
template <bool MAP>
__global__ void scatter_k(const int* __restrict__ esrc, const int* __restrict__ edst,
                          const int* __restrict__ nid, const int* __restrict__ rstart,
                          int* __restrict__ cursor, int* __restrict__ csr, int E) {
    int e = blockIdx.x * 256 + threadIdx.x;
    if (e >= E) return;
    int d = edst[e];
    int pos = rstart[d] + atomicAdd(&cursor[d], 1);
    int s = esrc[e];
    csr[pos] = MAP ? nid[s] : s;
}

// ------------------------------------------------------------------
// Mean aggregation: one block per dst node, F threads (one column each)
// ------------------------------------------------------------------
template <int F>
__global__ void agg_k(const float* __restrict__ X, const int* __restrict__ csr,
                      const int* __restrict__ rstart, const int* __restrict__ cnt,
                      float* __restrict__ mean) {
    int d = blockIdx.x;
    int t = threadIdx.x;  // 0..F-1
    int beg = rstart[d];
    int num = cnt[d];
    float acc = 0.f;
    int e = 0;
    for (; e + 4 <= num; e += 4) {
        int r0 = csr[beg + e + 0];
        int r1 = csr[beg + e + 1];
        int r2 = csr[beg + e + 2];
        int r3 = csr[beg + e + 3];
        float a0 = X[(size_t)r0 * F + t];
        float a1 = X[(size_t)r1 * F + t];
        float a2 = X[(size_t)r2 * F + t];
        float a3 = X[(size_t)r3 * F + t];
        acc += (a0 + a1) + (a2 + a3);
    }
    for (; e < num; ++e) acc += X[(size_t)csr[beg + e] * F + t];
    float denom = (float)((num > 0) ? num : 1);
    mean[(size_t)d * F + t] = acc / denom;
}

// ------------------------------------------------------------------
// Fused concat-GEMM: C[M,N] = [A0 | Asrc(gathered)] @ [B0 ; B1] + bias (,ReLU)
// A0 row length = KHALF (indexed by output row), Asrc row length = KHALF
// (indexed by nid[row] if GATHER else row). BM=64 BN=64 BK=16, 256 thr, 4x4.
// ------------------------------------------------------------------
template <int KHALF, int NCOLS, bool GATHER, bool RELU>
__global__ __launch_bounds__(256) void gemm_k(
    const float* __restrict__ A0, const float* __restrict__ Asrc,
    const int* __restrict__ nid, const float* __restrict__ B0,
    const float* __restrict__ B1, const float* __restrict__ bias,
    float* __restrict__ C, int M) {
    constexpr int BM = 64, BN = 64, BK = 16;
    __shared__ float As[BK][BM + 4];
    __shared__ float Bs[BK][BN];
    __shared__ int rowidx[BM];

    int t = threadIdx.x;
    int tx = t & 15, ty = t >> 4;
    int row0 = blockIdx.x * BM;
    int col0 = blockIdx.y * BN;

    if (t < BM) {
        int r = row0 + t;
        rowidx[t] = GATHER ? nid[r] : r;
    }
    __syncthreads();

    // A stage mapping: thread -> (row ar, 4 k's at ak)
    int ar = t >> 2, ak = (t & 3) * 4;
    // B stage mapping: thread -> (k bk, 4 cols at bj)
    int bk = t >> 4, bj = (t & 15) * 4;

    float acc[4][4] = {};
    constexpr int KT = 2 * KHALF;
    for (int k0 = 0; k0 < KT; k0 += BK) {
        bool first = (k0 < KHALF);
        const float* asrc = first ? A0 : Asrc;
        int kof = first ? k0 : (k0 - KHALF);
        int arow = first ? (row0 + ar) : rowidx[ar];
        float4 av = *(const float4*)&asrc[(size_t)arow * KHALF + kof + ak];
        As[ak + 0][ar] = av.x;
        As[ak + 1][ar] = av.y;
        As[ak + 2][ar] = av.z;
        As[ak + 3][ar] = av.w;
        const float* bsrc = first ? B0 : B1;
        float4 bv = *(const float4*)&bsrc[(size_t)(kof + bk) * NCOLS + col0 + bj];
        *(float4*)&Bs[bk][bj] = bv;
        __syncthreads();
#pragma unroll
        for (int k = 0; k < BK; ++k) {
            float4 a4 = *(const float4*)&As[k][ty * 4];
            float4 b4 = *(const float4*)&Bs[k][tx * 4];
            float a[4] = {a4.x, a4.y, a4.z, a4.w};
            float b[4] = {b4.x, b4.y, b4.z, b4.w};
#pragma unroll
            for (int i = 0; i < 4; ++i)
#pragma unroll
                for (int j = 0; j < 4; ++j) acc[i][j] += a[i] * b[j];
        }
        __syncthreads();
    }

#pragma unroll
    for (int i = 0; i < 4; ++i) {
        int r = row0 + ty * 4 + i;
        int c = col0 + tx * 4;
        float4 o;
        o.x = acc[i][0] + bias[c + 0];
        o.y = acc[i][1] + bias[c + 1];
        o.z = acc[i][2] + bias[c + 2];
        o.w = acc[i][3] + bias[c + 3];
        if (RELU) {
            o.x = fmaxf(o.x, 0.f);
            o.y = fmaxf(o.y, 0.f);
            o.z = fmaxf(o.z, 0.f);
            o.w = fmaxf(o.w, 0.f);
        }
        *(float4*)&C[(size_t)r * NCOLS + c] = o;
    }
}

// ------------------------------------------------------------------
extern "C" void kernel_launch(void* const* d_in, const int* in_sizes, int n_in,
                              void* d_out, int out_size, void* d_ws, size_t ws_size,
                              hipStream_t stream) {
    const float* x_all = (const float*)d_in[0];
    const int* n_id = (const int*)d_in[1];
    const int* esrc0 = (const int*)d_in[2];
    const int* edst0 = (const int*)d_in[3];
    const int* esrc1 = (const int*)d_in[4];
    const int* edst1 = (const int*)d_in[5];
    const float* W_l0 = (const float*)d_in[6];
    const float* b_l0 = (const float*)d_in[7];
    const float* W_r0 = (const float*)d_in[8];
    const float* W_l1 = (const float*)d_in[9];
    const float* b_l1 = (const float*)d_in[10];
    const float* W_r1 = (const float*)d_in[11];

    char* ws = (char*)d_ws;
    size_t off = 0;
    auto alloc = [&](size_t bytes) {
        off = (off + 255) & ~(size_t)255;
        void* p = ws + off;
        off += bytes;
        return p;
    };
    int* cnt0 = (int*)alloc((size_t)ND0 * 4);
    int* rs0 = (int*)alloc((size_t)ND0 * 4);
    int* cur0 = (int*)alloc((size_t)ND0 * 4);
    int* csr0 = (int*)alloc((size_t)NE0 * 4);
    int* cnt1 = (int*)alloc((size_t)ND1 * 4);
    int* rs1 = (int*)alloc((size_t)ND1 * 4);
    int* cur1 = (int*)alloc((size_t)ND1 * 4);
    int* csr1 = (int*)alloc((size_t)NE1 * 4);
    int* bsum = (int*)alloc(1024 * 4);
    int* boff = (int*)alloc(1024 * 4);
    float* mean0 = (float*)alloc((size_t)ND0 * F_IN * 4);
    float* h = (float*)alloc((size_t)ND0 * HID * 4);
    float* mean1 = (float*)alloc((size_t)ND1 * HID * 4);

    hipMemsetAsync(cnt0, 0, (size_t)ND0 * 4, stream);
    hipMemsetAsync(cur0, 0, (size_t)ND0 * 4, stream);
    hipMemsetAsync(cnt1, 0, (size_t)ND1 * 4, stream);
    hipMemsetAsync(cur1, 0, (size_t)ND1 * 4, stream);

    // ---------------- Layer 1 ----------------
    hist_k<<<(NE0 + 255) / 256, 256, 0, stream>>>(edst0, cnt0, NE0);
    scan_part_k<<<ND0 / 1024, 256, 0, stream>>>(cnt0, rs0, bsum, ND0);
    scan_part_k<<<1, 256, 0, stream>>>(bsum, boff, nullptr, ND0 / 1024);
    scan_add_k<<<(ND0 + 255) / 256, 256, 0, stream>>>(rs0, boff, ND0);
    scatter_k<true><<<(NE0 + 255) / 256, 256, 0, stream>>>(esrc0, edst0, n_id, rs0,
                                                           cur0, csr0, NE0);
    agg_k<F_IN><<<ND0, F_IN, 0, stream>>>(x_all, csr0, rs0, cnt0, mean0);
    gemm_k<F_IN, HID, true, true>
        <<<dim3(ND0 / 64, HID / 64), 256, 0, stream>>>(mean0, x_all, n_id, W_l0,
                                                       W_r0, b_l0, h, ND0);

    // ---------------- Layer 2 ----------------
    hist_k<<<(NE1 + 255) / 256, 256, 0, stream>>>(edst1, cnt1, NE1);
    scan_part_k<<<ND1 / 1024, 256, 0, stream>>>(cnt1, rs1, bsum, ND1);
    scan_part_k<<<1, 256, 0, stream>>>(bsum, boff, nullptr, ND1 / 1024);
    scan_add_k<<<(ND1 + 255) / 256, 256, 0, stream>>>(rs1, boff, ND1);
    scatter_k<false><<<(NE1 + 255) / 256, 256, 0, stream>>>(esrc1, edst1, nullptr,
                                                            rs1, cur1, csr1, NE1);
    agg_k<HID><<<ND1, HID, 0, stream>>>(h, csr1, rs1, cnt1, mean1);
    gemm_k<HID, F_OUT, false, false>
        <<<dim3(ND1 / 64, F_OUT / 64), 256, 0, stream>>>(mean1, h, nullptr, W_l1,
                                                         W_r1, b_l1, (float*)d_out,
                                                         ND1);
}

// Round 2
// 349.341 us; speedup vs baseline: 1.4055x; 1.4055x over previous
//
#include <hip/hip_runtime.h>

// Problem constants (from setup_inputs)
#define ND0 90112
#define ND1 8192
#define NE0 1351680
#define NE1 81920
#define F_IN 128
#define HID 256
#define F_OUT 128

typedef __attribute__((ext_vector_type(8))) short short8;
typedef __attribute__((ext_vector_type(4))) float f32x4;

__device__ inline ushort f2bf(float f) {
    unsigned u = __float_as_uint(f);
    return (ushort)((u + 0x7fffu + ((u >> 16) & 1u)) >> 16);
}
__device__ inline float bf2f(ushort h) {
    return __uint_as_float(((unsigned)h) << 16);
}

// ------------------------------------------------------------------
// CSR build: histogram -> exclusive scan (two-level) -> scatter
// ------------------------------------------------------------------
__global__ void hist_k(const int* __restrict__ dst, int* __restrict__ cnt, int E) {
    int e = blockIdx.x * 256 + threadIdx.x;
    if (e < E) atomicAdd(&cnt[dst[e]], 1);
}

__global__ void scan_part_k(const int* __restrict__ in, int* __restrict__ out,
                            int* __restrict__ bsum, int n) {
    __shared__ int sh[256];
    int base = blockIdx.x * 1024;
    int t = threadIdx.x;
    int v[4];
    int s = 0;
#pragma unroll
    for (int i = 0; i < 4; ++i) {
        int idx = base + t * 4 + i;
        v[i] = (idx < n) ? in[idx] : 0;
        s += v[i];
    }
    sh[t] = s;
    __syncthreads();
    for (int off = 1; off < 256; off <<= 1) {
        int x = (t >= off) ? sh[t - off] : 0;
        __syncthreads();
        sh[t] += x;
        __syncthreads();
    }
    int excl = (t == 0) ? 0 : sh[t - 1];
    if (t == 255 && bsum) bsum[blockIdx.x] = sh[255];
#pragma unroll
    for (int i = 0; i < 4; ++i) {
        int idx = base + t * 4 + i;
        if (idx < n) out[idx] = excl;
        excl += v[i];
    }
}

__global__ void scan_add_k(int* __restrict__ out, const int* __restrict__ boff, int n) {
    int i = blockIdx.x * 256 + threadIdx.x;
    if (i < n) out[i] += boff[i >> 10];
}

template <bool MAP>
__global__ void scatter_k(const int* __restrict__ esrc, const int* __restrict__ edst,
                          const int* __restrict__ nid, const int* __restrict__ rstart,
                          int* __restrict__ cursor, int* __restrict__ csr, int E) {
    int e = blockIdx.x * 256 + threadIdx.x;
    if (e >= E) return;
    int d = edst[e];
    int pos = rstart[d] + atomicAdd(&cursor[d], 1);
    int s = esrc[e];
    csr[pos] = MAP ? nid[s] : s;
}

// ------------------------------------------------------------------
// Mean aggregation: one block per dst node, F threads (one column each).
// Accumulates fp32, stores bf16.
// ------------------------------------------------------------------
template <int F, bool IN_BF16>
__global__ void agg_k(const void* __restrict__ Xv, const int* __restrict__ csr,
                      const int* __restrict__ rstart, const int* __restrict__ cnt,
                      ushort* __restrict__ mean) {
    const float* Xf = (const float*)Xv;
    const ushort* Xh = (const ushort*)Xv;
    int d = blockIdx.x;
    int t = threadIdx.x;  // 0..F-1
    int beg = rstart[d];
    int num = cnt[d];
    float acc = 0.f;
    int e = 0;
    for (; e + 4 <= num; e += 4) {
        int r0 = csr[beg + e + 0];
        int r1 = csr[beg + e + 1];
        int r2 = csr[beg + e + 2];
        int r3 = csr[beg + e + 3];
        float a0, a1, a2, a3;
        if (IN_BF16) {
            a0 = bf2f(Xh[(size_t)r0 * F + t]);
            a1 = bf2f(Xh[(size_t)r1 * F + t]);
            a2 = bf2f(Xh[(size_t)r2 * F + t]);
            a3 = bf2f(Xh[(size_t)r3 * F + t]);
        } else {
            a0 = Xf[(size_t)r0 * F + t];
            a1 = Xf[(size_t)r1 * F + t];
            a2 = Xf[(size_t)r2 * F + t];
            a3 = Xf[(size_t)r3 * F + t];
        }
        acc += (a0 + a1) + (a2 + a3);
    }
    for (; e < num; ++e) {
        int r = csr[beg + e];
        acc += IN_BF16 ? bf2f(Xh[(size_t)r * F + t]) : Xf[(size_t)r * F + t];
    }
    float denom = (float)((num > 0) ? num : 1);
    mean[(size_t)d * F + t] = f2bf(acc / denom);
}

// ------------------------------------------------------------------
// Gather + fp32->bf16 convert: out[r][c] = bf16(X[nid[r]][c]), F=128
// ------------------------------------------------------------------
__global__ void gather_bf_k(const float* __restrict__ X, const int* __restrict__ nid,
                            ushort* __restrict__ out, int rows) {
    int idx = blockIdx.x * 256 + threadIdx.x;  // one thread per 4 elems
    int r = idx >> 5;                          // F_IN/4 = 32 chunks per row
    int c4 = (idx & 31) * 4;
    if (r >= rows) return;
    float4 v = *(const float4*)&X[(size_t)nid[r] * F_IN + c4];
    ushort4 o;
    o.x = f2bf(v.x);
    o.y = f2bf(v.y);
    o.z = f2bf(v.z);
    o.w = f2bf(v.w);
    *(ushort4*)&out[(size_t)r * F_IN + c4] = o;
}

// ------------------------------------------------------------------
// Weight transpose+convert: Bt[n][k] (k in [0,2KH)) from Wl,Wr [KH][N] fp32
// ------------------------------------------------------------------
__global__ void wtrans_k(const float* __restrict__ Wl, const float* __restrict__ Wr,
                         ushort* __restrict__ Bt, int KH, int N) {
    int idx = blockIdx.x * 256 + threadIdx.x;
    int K2 = 2 * KH;
    if (idx >= N * K2) return;
    int n = idx / K2;
    int k = idx - n * K2;
    float v = (k < KH) ? Wl[(size_t)k * N + n] : Wr[(size_t)(k - KH) * N + n];
    Bt[idx] = f2bf(v);
}

// ------------------------------------------------------------------
// bf16 MFMA concat-K GEMM:
//   C[M][NCOLS] = [A0 | A1] @ Bt^T + bias (, ReLU)
// A0, A1: [M][KHALF] bf16 row-major. Bt: [NCOLS][2*KHALF] bf16.
// BM=128 BN=64 BK=64, 256 threads (4 waves, 2x2), wave tile 64x32,
// fragments 4(M) x 2(N) of 16x16x32.
// ------------------------------------------------------------------
template <int KHALF, int NCOLS, bool RELU, bool OUT_BF16>
__global__ __launch_bounds__(256) void mgemm_k(
    const ushort* __restrict__ A0, const ushort* __restrict__ A1,
    const ushort* __restrict__ Bt, const float* __restrict__ bias,
    void* __restrict__ Cv, int M) {
    __shared__ ushort As[128][72];  // +8 elem pad: stride 144 B (16B-aligned, ~2-way banks)
    __shared__ ushort Bs[64][72];

    int t = threadIdx.x;
    int row0 = blockIdx.x * 128;
    int col0 = blockIdx.y * 64;
    int lane = t & 63;
    int w = t >> 6;
    int wm = w >> 1, wn = w & 1;  // 2x2 wave grid
    int lr = lane & 15;
    int lk = (lane >> 4) * 8;

    // staging maps
    int ar = t >> 1, ac = (t & 1) * 32;  // A: 2 threads/row, 32 elems each
    int bn = t >> 2, bc = (t & 3) * 16;  // B: 4 threads/row, 16 elems each

    f32x4 acc[4][2] = {};

    for (int k0 = 0; k0 < 2 * KHALF; k0 += 64) {
        const ushort* Asrc = (k0 < KHALF) ? A0 : A1;
        int kof = (k0 < KHALF) ? k0 : (k0 - KHALF);
        const ushort* ap = &Asrc[(size_t)(row0 + ar) * KHALF + kof + ac];
        const ushort* bp = &Bt[(size_t)(col0 + bn) * (2 * KHALF) + k0 + bc];
        short8 av0 = *(const short8*)(ap);
        short8 av1 = *(const short8*)(ap + 8);
        short8 av2 = *(const short8*)(ap + 16);
        short8 av3 = *(const short8*)(ap + 24);
        short8 bv0 = *(const short8*)(bp);
        short8 bv1 = *(const short8*)(bp + 8);
        __syncthreads();  // previous tile's compute done
        *(short8*)&As[ar][ac + 0] = av0;
        *(short8*)&As[ar][ac + 8] = av1;
        *(short8*)&As[ar][ac + 16] = av2;
        *(short8*)&As[ar][ac + 24] = av3;
        *(short8*)&Bs[bn][bc + 0] = bv0;
        *(short8*)&Bs[bn][bc + 8] = bv1;
        __syncthreads();
#pragma unroll
        for (int ks = 0; ks < 64; ks += 32) {
            short8 bf0 = *(const short8*)&Bs[wn * 32 + lr][ks + lk];
            short8 bf1 = *(const short8*)&Bs[wn * 32 + 16 + lr][ks + lk];
#pragma unroll
            for (int mi = 0; mi < 4; ++mi) {
                short8 af = *(const short8*)&As[wm * 64 + mi * 16 + lr][ks + lk];
                acc[mi][0] = __builtin_amdgcn_mfma_f32_16x16x32_bf16(af, bf0, acc[mi][0], 0, 0, 0);
                acc[mi][1] = __builtin_amdgcn_mfma_f32_16x16x32_bf16(af, bf1, acc[mi][1], 0, 0, 0);
            }
        }
    }

    // epilogue: D row=(lane>>4)*4+j, col=lane&15 (verified mapping)
    int orow = row0 + wm * 64;
    int ocol = col0 + wn * 32;
#pragma unroll
    for (int mi = 0; mi < 4; ++mi) {
#pragma unroll
        for (int ni = 0; ni < 2; ++ni) {
            int c = ocol + ni * 16 + lr;
            float bi = bias[c];
#pragma unroll
            for (int j = 0; j < 4; ++j) {
                int r = orow + mi * 16 + (lane >> 4) * 4 + j;
                float v = acc[mi][ni][j] + bi;
                if (RELU) v = fmaxf(v, 0.f);
                if (OUT_BF16)
                    ((ushort*)Cv)[(size_t)r * NCOLS + c] = f2bf(v);
                else
                    ((float*)Cv)[(size_t)r * NCOLS + c] = v;
            }
        }
    }
}

// ------------------------------------------------------------------
extern "C" void kernel_launch(void* const* d_in, const int* in_sizes, int n_in,
                              void* d_out, int out_size, void* d_ws, size_t ws_size,
                              hipStream_t stream) {
    const float* x_all = (const float*)d_in[0];
    const int* n_id = (const int*)d_in[1];
    const int* esrc0 = (const int*)d_in[2];
    const int* edst0 = (const int*)d_in[3];
    const int* esrc1 = (const int*)d_in[4];
    const int* edst1 = (const int*)d_in[5];
    const float* W_l0 = (const float*)d_in[6];
    const float* b_l0 = (const float*)d_in[7];
    const float* W_r0 = (const float*)d_in[8];
    const float* W_l1 = (const float*)d_in[9];
    const float* b_l1 = (const float*)d_in[10];
    const float* W_r1 = (const float*)d_in[11];

    char* ws = (char*)d_ws;
    size_t off = 0;
    auto alloc = [&](size_t bytes) {
        off = (off + 255) & ~(size_t)255;
        void* p = ws + off;
        off += bytes;
        return p;
    };
    int* cnt0 = (int*)alloc((size_t)ND0 * 4);
    int* rs0 = (int*)alloc((size_t)ND0 * 4);
    int* cur0 = (int*)alloc((size_t)ND0 * 4);
    int* csr0 = (int*)alloc((size_t)NE0 * 4);
    int* cnt1 = (int*)alloc((size_t)ND1 * 4);
    int* rs1 = (int*)alloc((size_t)ND1 * 4);
    int* cur1 = (int*)alloc((size_t)ND1 * 4);
    int* csr1 = (int*)alloc((size_t)NE1 * 4);
    int* bsum = (int*)alloc(1024 * 4);
    int* boff = (int*)alloc(1024 * 4);
    ushort* mean0 = (ushort*)alloc((size_t)ND0 * F_IN * 2);
    ushort* xdst = (ushort*)alloc((size_t)ND0 * F_IN * 2);
    ushort* h = (ushort*)alloc((size_t)ND0 * HID * 2);
    ushort* mean1 = (ushort*)alloc((size_t)ND1 * HID * 2);
    ushort* Bt0 = (ushort*)alloc((size_t)HID * (2 * F_IN) * 2);
    ushort* Bt1 = (ushort*)alloc((size_t)F_OUT * (2 * HID) * 2);

    hipMemsetAsync(cnt0, 0, (size_t)ND0 * 4, stream);
    hipMemsetAsync(cur0, 0, (size_t)ND0 * 4, stream);
    hipMemsetAsync(cnt1, 0, (size_t)ND1 * 4, stream);
    hipMemsetAsync(cur1, 0, (size_t)ND1 * 4, stream);

    // weight prep (tiny)
    wtrans_k<<<(HID * 2 * F_IN + 255) / 256, 256, 0, stream>>>(W_l0, W_r0, Bt0, F_IN, HID);
    wtrans_k<<<(F_OUT * 2 * HID + 255) / 256, 256, 0, stream>>>(W_l1, W_r1, Bt1, HID, F_OUT);
    // x_dst gather -> bf16
    gather_bf_k<<<((ND0 * 32) + 255) / 256, 256, 0, stream>>>(x_all, n_id, xdst, ND0);

    // ---------------- Layer 1 ----------------
    hist_k<<<(NE0 + 255) / 256, 256, 0, stream>>>(edst0, cnt0, NE0);
    scan_part_k<<<ND0 / 1024, 256, 0, stream>>>(cnt0, rs0, bsum, ND0);
    scan_part_k<<<1, 256, 0, stream>>>(bsum, boff, nullptr, ND0 / 1024);
    scan_add_k<<<(ND0 + 255) / 256, 256, 0, stream>>>(rs0, boff, ND0);
    scatter_k<true><<<(NE0 + 255) / 256, 256, 0, stream>>>(esrc0, edst0, n_id, rs0,
                                                           cur0, csr0, NE0);
    agg_k<F_IN, false><<<ND0, F_IN, 0, stream>>>(x_all, csr0, rs0, cnt0, mean0);
    mgemm_k<F_IN, HID, true, true>
        <<<dim3(ND0 / 128, HID / 64), 256, 0, stream>>>(mean0, xdst, Bt0, b_l0, h, ND0);

    // ---------------- Layer 2 ----------------
    hist_k<<<(NE1 + 255) / 256, 256, 0, stream>>>(edst1, cnt1, NE1);
    scan_part_k<<<ND1 / 1024, 256, 0, stream>>>(cnt1, rs1, bsum, ND1);
    scan_part_k<<<1, 256, 0, stream>>>(bsum, boff, nullptr, ND1 / 1024);
    scan_add_k<<<(ND1 + 255) / 256, 256, 0, stream>>>(rs1, boff, ND1);
    scatter_k<false><<<(NE1 + 255) / 256, 256, 0, stream>>>(esrc1, edst1, nullptr,
                                                            rs1, cur1, csr1, NE1);
    agg_k<HID, true><<<ND1, HID, 0, stream>>>(h, csr1, rs1, cnt1, mean1);
    mgemm_k<HID, F_OUT, false, false>
        <<<dim3(ND1 / 128, F_OUT / 64), 256, 0, stream>>>(mean1, h, Bt1, b_l1,
                                                          (float*)d_out, ND1);
}

// Round 3
// 347.781 us; speedup vs baseline: 1.4118x; 1.0045x over previous
//
#include <hip/hip_runtime.h>

// Problem constants (from setup_inputs)
#define ND0 90112
#define ND1 8192
#define NDT (ND0 + ND1)         // 98304 combined dst space
#define NE0 1351680
#define NE1 81920
#define NET (NE0 + NE1)
#define F_IN 128
#define HID 256
#define F_OUT 128

typedef __attribute__((ext_vector_type(8))) short short8;
typedef __attribute__((ext_vector_type(4))) float f32x4;

__device__ inline ushort f2bf(float f) {
    unsigned u = __float_as_uint(f);
    return (ushort)((u + 0x7fffu + ((u >> 16) & 1u)) >> 16);
}
__device__ inline float bf2f(ushort h) {
    return __uint_as_float(((unsigned)h) << 16);
}

// ------------------------------------------------------------------
// Combined CSR build over [layer0 dsts | layer1 dsts]
// ------------------------------------------------------------------
__global__ void hist_all_k(const int* __restrict__ edst0, const int* __restrict__ edst1,
                           int* __restrict__ cnt) {
    int e = blockIdx.x * 256 + threadIdx.x;
    if (e < NE0)
        atomicAdd(&cnt[edst0[e]], 1);
    else if (e < NET)
        atomicAdd(&cnt[ND0 + edst1[e - NE0]], 1);
}

// 96 blocks x 1024-elem chunks: per-chunk exclusive scan + chunk totals
__global__ void scan_part_k(const int* __restrict__ in, int* __restrict__ out,
                            int* __restrict__ bsum) {
    __shared__ int sh[256];
    int base = blockIdx.x * 1024;
    int t = threadIdx.x;
    int v[4];
    int s = 0;
#pragma unroll
    for (int i = 0; i < 4; ++i) {
        v[i] = in[base + t * 4 + i];
        s += v[i];
    }
    sh[t] = s;
    __syncthreads();
    for (int off = 1; off < 256; off <<= 1) {
        int x = (t >= off) ? sh[t - off] : 0;
        __syncthreads();
        sh[t] += x;
        __syncthreads();
    }
    int excl = (t == 0) ? 0 : sh[t - 1];
    if (t == 255) bsum[blockIdx.x] = sh[255];
#pragma unroll
    for (int i = 0; i < 4; ++i) {
        out[base + t * 4 + i] = excl;
        excl += v[i];
    }
}

// add prefix of chunk totals; each block recomputes the tiny prefix itself
__global__ void scan_fix_k(int* __restrict__ out, const int* __restrict__ bsum) {
    __shared__ int pref;
    int chunk = (blockIdx.x * 256) >> 10;
    if (threadIdx.x == 0) {
        int s = 0;
        for (int i = 0; i < chunk; ++i) s += bsum[i];
        pref = s;
    }
    __syncthreads();
    out[blockIdx.x * 256 + threadIdx.x] += pref;
}

// scatter both layers; layer0 src pre-mapped through n_id
__global__ void scatter_all_k(const int* __restrict__ esrc0, const int* __restrict__ edst0,
                              const int* __restrict__ esrc1, const int* __restrict__ edst1,
                              const int* __restrict__ nid, const int* __restrict__ rstart,
                              int* __restrict__ cursor, int* __restrict__ csr) {
    int e = blockIdx.x * 256 + threadIdx.x;
    if (e >= NET) return;
    int d, s;
    if (e < NE0) {
        d = edst0[e];
        s = nid[esrc0[e]];
    } else {
        int e1 = e - NE0;
        d = ND0 + edst1[e1];
        s = esrc1[e1];
    }
    int pos = rstart[d] + atomicAdd(&cursor[d], 1);
    csr[pos] = s;
}

// ------------------------------------------------------------------
// Mean aggregation, vectorized 16B/lane.
// 128 threads = 32 col-groups x 4 edge-slots; 8-edge unrolled loop.
// Optionally fuses the x_dst row gather (layer 0).
// ------------------------------------------------------------------
template <int F, bool IN_BF16, bool GATHER>
__global__ __launch_bounds__(128) void agg_k(
    const void* __restrict__ Xv, const int* __restrict__ csr,
    const int* __restrict__ rstart, const int* __restrict__ cnt, int dofs,
    ushort* __restrict__ mean, const float* __restrict__ Xg,
    const int* __restrict__ nid, ushort* __restrict__ xdst) {
    constexpr int EPT = IN_BF16 ? 8 : 4;  // elems per thread (16 B)
    __shared__ float sh[128][EPT];

    int d = blockIdx.x;
    int t = threadIdx.x;
    int cg = t & 31, slot = t >> 5;
    int beg = rstart[dofs + d];
    int num = cnt[dofs + d];

    float acc[EPT] = {};
    const float* Xf = (const float*)Xv;
    const ushort* Xh = (const ushort*)Xv;

    for (int e = 0; e < num; e += 8) {
        int i0 = e + slot, i1 = e + 4 + slot;
        bool v0 = i0 < num, v1 = i1 < num;
        int r0 = v0 ? csr[beg + i0] : 0;
        int r1 = v1 ? csr[beg + i1] : 0;
        if (IN_BF16) {
            if (v0) {
                short8 x = *(const short8*)&Xh[(size_t)r0 * F + cg * 8];
#pragma unroll
                for (int i = 0; i < 8; ++i) acc[i] += bf2f((ushort)x[i]);
            }
            if (v1) {
                short8 x = *(const short8*)&Xh[(size_t)r1 * F + cg * 8];
#pragma unroll
                for (int i = 0; i < 8; ++i) acc[i] += bf2f((ushort)x[i]);
            }
        } else {
            if (v0) {
                float4 x = *(const float4*)&Xf[(size_t)r0 * F + cg * 4];
                acc[0] += x.x; acc[1] += x.y; acc[2] += x.z; acc[3] += x.w;
            }
            if (v1) {
                float4 x = *(const float4*)&Xf[(size_t)r1 * F + cg * 4];
                acc[0] += x.x; acc[1] += x.y; acc[2] += x.z; acc[3] += x.w;
            }
        }
    }

    // fused x_dst gather (independent of edge loop; overlaps reduction)
    float xv = 0.f;
    if (GATHER) xv = Xg[(size_t)nid[d] * 128 + t];

#pragma unroll
    for (int i = 0; i < EPT; ++i) sh[t][i] = acc[i];
    __syncthreads();
    if (t < 32) {
        float inv = 1.f / (float)((num > 0) ? num : 1);
        if (IN_BF16) {
            short8 ov;
#pragma unroll
            for (int i = 0; i < 8; ++i) {
                float s = sh[t][i] + sh[t + 32][i] + sh[t + 64][i] + sh[t + 96][i];
                ov[i] = (short)f2bf(s * inv);
            }
            *(short8*)&mean[(size_t)d * F + t * 8] = ov;
        } else {
            ushort4 ov;
            float s0 = sh[t][0] + sh[t + 32][0] + sh[t + 64][0] + sh[t + 96][0];
            float s1 = sh[t][1] + sh[t + 32][1] + sh[t + 64][1] + sh[t + 96][1];
            float s2 = sh[t][2] + sh[t + 32][2] + sh[t + 64][2] + sh[t + 96][2];
            float s3 = sh[t][3] + sh[t + 32][3] + sh[t + 64][3] + sh[t + 96][3];
            ov.x = f2bf(s0 * inv); ov.y = f2bf(s1 * inv);
            ov.z = f2bf(s2 * inv); ov.w = f2bf(s3 * inv);
            *(ushort4*)&mean[(size_t)d * F + t * 4] = ov;
        }
    }
    if (GATHER) xdst[(size_t)d * 128 + t] = f2bf(xv);
}

// ------------------------------------------------------------------
// Merged weight transpose+convert for both layers
// ------------------------------------------------------------------
__global__ void wtrans_all_k(const float* __restrict__ Wl0, const float* __restrict__ Wr0,
                             const float* __restrict__ Wl1, const float* __restrict__ Wr1,
                             ushort* __restrict__ Bt0, ushort* __restrict__ Bt1) {
    int idx = blockIdx.x * 256 + threadIdx.x;
    constexpr int N0 = HID * 2 * F_IN;  // 65536
    if (idx < N0) {
        int K2 = 2 * F_IN;
        int n = idx / K2, k = idx - n * K2;
        float v = (k < F_IN) ? Wl0[(size_t)k * HID + n] : Wr0[(size_t)(k - F_IN) * HID + n];
        Bt0[idx] = f2bf(v);
    } else {
        int j = idx - N0;  // F_OUT * 2 * HID = 65536
        int K2 = 2 * HID;
        int n = j / K2, k = j - n * K2;
        float v = (k < HID) ? Wl1[(size_t)k * F_OUT + n] : Wr1[(size_t)(k - HID) * F_OUT + n];
        Bt1[j] = f2bf(v);
    }
}

// ------------------------------------------------------------------
// bf16 MFMA concat-K GEMM: C[M][NCOLS] = [A0 | A1] @ Bt^T + bias (,ReLU)
// A0,A1: [M][KHALF] bf16. Bt: [NCOLS][2*KHALF] bf16.
// BM x 64 tile, BK=64, 256 threads (4 waves 2x2), 16x16x32 MFMA.
// ------------------------------------------------------------------
template <int BM, int KHALF, int NCOLS, bool RELU, bool OUT_BF16>
__global__ __launch_bounds__(256) void mgemm_k(
    const ushort* __restrict__ A0, const ushort* __restrict__ A1,
    const ushort* __restrict__ Bt, const float* __restrict__ bias,
    void* __restrict__ Cv, int M) {
    constexpr int MI = BM / 32;       // M-fragments per wave
    constexpr int TPR = 256 / BM;     // staging threads per A row
    constexpr int AV = 64 / TPR / 8;  // short8 loads per thread (A)
    __shared__ ushort As[BM][72];
    __shared__ ushort Bs[64][72];

    int t = threadIdx.x;
    int row0 = blockIdx.x * BM;
    int col0 = blockIdx.y * 64;
    int lane = t & 63;
    int w = t >> 6, wm = w >> 1, wn = w & 1;
    int lr = lane & 15;
    int lk = (lane >> 4) * 8;

    int ar = t / TPR, ac = (t % TPR) * (64 / TPR);
    int bn = t >> 2, bc = (t & 3) * 16;

    f32x4 acc[MI][2] = {};

    for (int k0 = 0; k0 < 2 * KHALF; k0 += 64) {
        const ushort* Asrc = (k0 < KHALF) ? A0 : A1;
        int kof = (k0 < KHALF) ? k0 : (k0 - KHALF);
        const ushort* ap = &Asrc[(size_t)(row0 + ar) * KHALF + kof + ac];
        const ushort* bp = &Bt[(size_t)(col0 + bn) * (2 * KHALF) + k0 + bc];
        short8 av[AV];
#pragma unroll
        for (int i = 0; i < AV; ++i) av[i] = *(const short8*)(ap + 8 * i);
        short8 bv0 = *(const short8*)(bp);
        short8 bv1 = *(const short8*)(bp + 8);
        __syncthreads();  // previous tile's compute done
#pragma unroll
        for (int i = 0; i < AV; ++i) *(short8*)&As[ar][ac + 8 * i] = av[i];
        *(short8*)&Bs[bn][bc + 0] = bv0;
        *(short8*)&Bs[bn][bc + 8] = bv1;
        __syncthreads();
#pragma unroll
        for (int ks = 0; ks < 64; ks += 32) {
            short8 bf0 = *(const short8*)&Bs[wn * 32 + lr][ks + lk];
            short8 bf1 = *(const short8*)&Bs[wn * 32 + 16 + lr][ks + lk];
#pragma unroll
            for (int mi = 0; mi < MI; ++mi) {
                short8 af = *(const short8*)&As[wm * (BM / 2) + mi * 16 + lr][ks + lk];
                acc[mi][0] = __builtin_amdgcn_mfma_f32_16x16x32_bf16(af, bf0, acc[mi][0], 0, 0, 0);
                acc[mi][1] = __builtin_amdgcn_mfma_f32_16x16x32_bf16(af, bf1, acc[mi][1], 0, 0, 0);
            }
        }
    }

    int orow = row0 + wm * (BM / 2);
    int ocol = col0 + wn * 32;
#pragma unroll
    for (int mi = 0; mi < MI; ++mi) {
#pragma unroll
        for (int ni = 0; ni < 2; ++ni) {
            int c = ocol + ni * 16 + lr;
            float bi = bias[c];
#pragma unroll
            for (int j = 0; j < 4; ++j) {
                int r = orow + mi * 16 + (lane >> 4) * 4 + j;
                float v = acc[mi][ni][j] + bi;
                if (RELU) v = fmaxf(v, 0.f);
                if (OUT_BF16)
                    ((ushort*)Cv)[(size_t)r * NCOLS + c] = f2bf(v);
                else
                    ((float*)Cv)[(size_t)r * NCOLS + c] = v;
            }
        }
    }
}

// ------------------------------------------------------------------
extern "C" void kernel_launch(void* const* d_in, const int* in_sizes, int n_in,
                              void* d_out, int out_size, void* d_ws, size_t ws_size,
                              hipStream_t stream) {
    const float* x_all = (const float*)d_in[0];
    const int* n_id = (const int*)d_in[1];
    const int* esrc0 = (const int*)d_in[2];
    const int* edst0 = (const int*)d_in[3];
    const int* esrc1 = (const int*)d_in[4];
    const int* edst1 = (const int*)d_in[5];
    const float* W_l0 = (const float*)d_in[6];
    const float* b_l0 = (const float*)d_in[7];
    const float* W_r0 = (const float*)d_in[8];
    const float* W_l1 = (const float*)d_in[9];
    const float* b_l1 = (const float*)d_in[10];
    const float* W_r1 = (const float*)d_in[11];

    char* ws = (char*)d_ws;
    size_t off = 0;
    auto alloc = [&](size_t bytes) {
        off = (off + 255) & ~(size_t)255;
        void* p = ws + off;
        off += bytes;
        return p;
    };
    int* cntcur = (int*)alloc((size_t)2 * NDT * 4);  // [cnt | cursor], one memset
    int* cnt = cntcur;
    int* cur = cntcur + NDT;
    int* rs = (int*)alloc((size_t)NDT * 4);
    int* csr = (int*)alloc((size_t)NET * 4);
    int* bsum = (int*)alloc(1024 * 4);
    ushort* mean0 = (ushort*)alloc((size_t)ND0 * F_IN * 2);
    ushort* xdst = (ushort*)alloc((size_t)ND0 * F_IN * 2);
    ushort* h = (ushort*)alloc((size_t)ND0 * HID * 2);
    ushort* mean1 = (ushort*)alloc((size_t)ND1 * HID * 2);
    ushort* Bt0 = (ushort*)alloc((size_t)HID * (2 * F_IN) * 2);
    ushort* Bt1 = (ushort*)alloc((size_t)F_OUT * (2 * HID) * 2);

    hipMemsetAsync(cntcur, 0, (size_t)2 * NDT * 4, stream);

    // weight prep + CSR build (both layers combined)
    wtrans_all_k<<<512, 256, 0, stream>>>(W_l0, W_r0, W_l1, W_r1, Bt0, Bt1);
    hist_all_k<<<NET / 256, 256, 0, stream>>>(edst0, edst1, cnt);
    scan_part_k<<<NDT / 1024, 256, 0, stream>>>(cnt, rs, bsum);
    scan_fix_k<<<NDT / 256, 256, 0, stream>>>(rs, bsum);
    scatter_all_k<<<NET / 256, 256, 0, stream>>>(esrc0, edst0, esrc1, edst1, n_id,
                                                 rs, cur, csr);

    // ---------------- Layer 1 ----------------
    agg_k<F_IN, false, true><<<ND0, 128, 0, stream>>>(x_all, csr, rs, cnt, 0, mean0,
                                                      x_all, n_id, xdst);
    mgemm_k<128, F_IN, HID, true, true>
        <<<dim3(ND0 / 128, HID / 64), 256, 0, stream>>>(mean0, xdst, Bt0, b_l0, h, ND0);

    // ---------------- Layer 2 ----------------
    agg_k<HID, true, false><<<ND1, 128, 0, stream>>>(h, csr, rs, cnt, ND0, mean1,
                                                     nullptr, nullptr, nullptr);
    mgemm_k<64, HID, F_OUT, false, false>
        <<<dim3(ND1 / 64, F_OUT / 64), 256, 0, stream>>>(mean1, h, Bt1, b_l1,
                                                         (float*)d_out, ND1);
}

// Round 4
// 322.125 us; speedup vs baseline: 1.5243x; 1.0796x over previous
//
#include <hip/hip_runtime.h>

// Problem constants (from setup_inputs)
#define ND0 90112
#define ND1 8192
#define NDT (ND0 + ND1)         // 98304 combined dst space
#define NE0 1351680
#define NE1 81920
#define NET (NE0 + NE1)
#define F_IN 128
#define HID 256
#define F_OUT 128

typedef __attribute__((ext_vector_type(8))) short short8;
typedef __attribute__((ext_vector_type(4))) float f32x4;

__device__ inline ushort f2bf(float f) {
    unsigned u = __float_as_uint(f);
    return (ushort)((u + 0x7fffu + ((u >> 16) & 1u)) >> 16);
}
__device__ inline float bf2f(ushort h) {
    return __uint_as_float(((unsigned)h) << 16);
}

// ------------------------------------------------------------------
// Combined CSR build over [layer0 dsts | layer1 dsts]
// ------------------------------------------------------------------
__global__ void hist_all_k(const int* __restrict__ edst0, const int* __restrict__ edst1,
                           int* __restrict__ cnt) {
    int e = blockIdx.x * 256 + threadIdx.x;
    if (e < NE0)
        atomicAdd(&cnt[edst0[e]], 1);
    else if (e < NET)
        atomicAdd(&cnt[ND0 + edst1[e - NE0]], 1);
}

// 1024-elem chunks: per-chunk exclusive scan + chunk totals
__global__ void scan_part_k(const int* __restrict__ in, int* __restrict__ out,
                            int* __restrict__ bsum, int n) {
    __shared__ int sh[256];
    int base = blockIdx.x * 1024;
    int t = threadIdx.x;
    int v[4];
    int s = 0;
#pragma unroll
    for (int i = 0; i < 4; ++i) {
        int idx = base + t * 4 + i;
        v[i] = (idx < n) ? in[idx] : 0;
        s += v[i];
    }
    sh[t] = s;
    __syncthreads();
    for (int off = 1; off < 256; off <<= 1) {
        int x = (t >= off) ? sh[t - off] : 0;
        __syncthreads();
        sh[t] += x;
        __syncthreads();
    }
    int excl = (t == 0) ? 0 : sh[t - 1];
    if (t == 255 && bsum) bsum[blockIdx.x] = sh[255];
#pragma unroll
    for (int i = 0; i < 4; ++i) {
        int idx = base + t * 4 + i;
        if (idx < n) out[idx] = excl;
        excl += v[i];
    }
}

__global__ void scan_add_k(int* __restrict__ out, const int* __restrict__ boff, int n) {
    int i = blockIdx.x * 256 + threadIdx.x;
    if (i < n) out[i] += boff[i >> 10];
}

// scatter both layers; layer0 src pre-mapped through n_id
__global__ void scatter_all_k(const int* __restrict__ esrc0, const int* __restrict__ edst0,
                              const int* __restrict__ esrc1, const int* __restrict__ edst1,
                              const int* __restrict__ nid, const int* __restrict__ rstart,
                              int* __restrict__ cursor, int* __restrict__ csr) {
    int e = blockIdx.x * 256 + threadIdx.x;
    if (e >= NET) return;
    int d, s;
    if (e < NE0) {
        d = edst0[e];
        s = nid[esrc0[e]];
    } else {
        int e1 = e - NE0;
        d = ND0 + edst1[e1];
        s = esrc1[e1];
    }
    int pos = rstart[d] + atomicAdd(&cursor[d], 1);
    csr[pos] = s;
}

// ------------------------------------------------------------------
// Merged weight transpose+convert for both layers
// ------------------------------------------------------------------
__global__ void wtrans_all_k(const float* __restrict__ Wl0, const float* __restrict__ Wr0,
                             const float* __restrict__ Wl1, const float* __restrict__ Wr1,
                             ushort* __restrict__ Bt0, ushort* __restrict__ Bt1) {
    int idx = blockIdx.x * 256 + threadIdx.x;
    constexpr int N0 = HID * 2 * F_IN;  // 65536
    if (idx < N0) {
        int K2 = 2 * F_IN;
        int n = idx / K2, k = idx - n * K2;
        float v = (k < F_IN) ? Wl0[(size_t)k * HID + n] : Wr0[(size_t)(k - F_IN) * HID + n];
        Bt0[idx] = f2bf(v);
    } else {
        int j = idx - N0;  // F_OUT * 2 * HID = 65536
        int K2 = 2 * HID;
        int n = j / K2, k = j - n * K2;
        float v = (k < HID) ? Wl1[(size_t)k * F_OUT + n] : Wr1[(size_t)(k - HID) * F_OUT + n];
        Bt1[j] = f2bf(v);
    }
}

// ------------------------------------------------------------------
// FUSED layer-1: aggregate (mean) + x_dst gather -> LDS A-tile -> MFMA GEMM
//   h[128 rows][256] = relu([mean | x_dst] @ Bt0^T + bias)
// 704 blocks x 512 threads (8 waves). LDS: As 128x264 bf16 (67.6 KB) + Bs 9.2 KB.
// ------------------------------------------------------------------
__global__ __launch_bounds__(512) void fused1_k(
    const float* __restrict__ X, const int* __restrict__ csr,
    const int* __restrict__ rstart, const int* __restrict__ cnt,
    const int* __restrict__ nid, const ushort* __restrict__ Bt,
    const float* __restrict__ bias, ushort* __restrict__ C) {
    __shared__ ushort As[128][264];  // [row][mean(0..127) | xdst(128..255)], +8 pad
    __shared__ ushort Bs[64][72];
    __shared__ int s_beg[128], s_num[128], s_nid[128];

    int t = threadIdx.x;
    int row0 = blockIdx.x * 128;

    if (t < 128) {
        s_beg[t] = rstart[row0 + t];
        s_num[t] = cnt[row0 + t];
        s_nid[t] = nid[row0 + t];
    }
    __syncthreads();

    // ---------- phase 1: aggregate + gather ----------
    {
        int row = t >> 2, q = t & 3;  // q: which 32-col chunk
        int beg = s_beg[row], num = s_num[row];
        int gr = s_nid[row];
        // x_dst gather: issue early, consume after edge loop
        const float* gp = &X[(size_t)gr * F_IN + q * 32];
        float4 xg[8];
#pragma unroll
        for (int i = 0; i < 8; ++i) xg[i] = *(const float4*)(gp + i * 4);

        float acc[32] = {};
#pragma unroll 1
        for (int e = 0; e < num; ++e) {
            int r = csr[beg + e];
            const float* rp = &X[(size_t)r * F_IN + q * 32];
#pragma unroll
            for (int i = 0; i < 8; ++i) {
                float4 v = *(const float4*)(rp + i * 4);
                acc[i * 4 + 0] += v.x;
                acc[i * 4 + 1] += v.y;
                acc[i * 4 + 2] += v.z;
                acc[i * 4 + 3] += v.w;
            }
        }
        float inv = 1.f / (float)((num > 0) ? num : 1);
#pragma unroll
        for (int i = 0; i < 4; ++i) {
            short8 o;
#pragma unroll
            for (int j = 0; j < 8; ++j) o[j] = (short)f2bf(acc[i * 8 + j] * inv);
            *(short8*)&As[row][q * 32 + i * 8] = o;
        }
        const float* xf = (const float*)xg;
#pragma unroll
        for (int i = 0; i < 4; ++i) {
            short8 o;
#pragma unroll
            for (int j = 0; j < 8; ++j) o[j] = (short)f2bf(xf[i * 8 + j]);
            *(short8*)&As[row][F_IN + q * 32 + i * 8] = o;
        }
    }
    // (phase-1 -> phase-2 ordering handled by the barrier before the Bs write)

    // ---------- phase 2: GEMM ----------
    int lane = t & 63;
    int w = t >> 6;
    int wm = w >> 2, wn2 = w & 3;  // 2(m) x 4(n) wave grid; wave tile 64m x 16n
    int lr = lane & 15, lj = lane >> 4;
    int bn = t >> 3, bk = (t & 7) * 8;  // B stage map: 64 n-rows x 64 k

    for (int nt = 0; nt < 4; ++nt) {
        f32x4 acc2[4] = {};
        for (int k0 = 0; k0 < 256; k0 += 64) {
            short8 bv = *(const short8*)&Bt[(size_t)(nt * 64 + bn) * 256 + k0 + bk];
            __syncthreads();  // As writes done (1st iter); prior Bs reads done
            *(short8*)&Bs[bn][bk] = bv;
            __syncthreads();
#pragma unroll
            for (int ks = 0; ks < 64; ks += 32) {
                short8 bf = *(const short8*)&Bs[wn2 * 16 + lr][ks + lj * 8];
#pragma unroll
                for (int mi = 0; mi < 4; ++mi) {
                    short8 af = *(const short8*)&As[wm * 64 + mi * 16 + lr][k0 + ks + lj * 8];
                    acc2[mi] = __builtin_amdgcn_mfma_f32_16x16x32_bf16(af, bf, acc2[mi], 0, 0, 0);
                }
            }
        }
        int c = nt * 64 + wn2 * 16 + lr;
        float bi = bias[c];
#pragma unroll
        for (int mi = 0; mi < 4; ++mi) {
#pragma unroll
            for (int j = 0; j < 4; ++j) {
                int r = row0 + wm * 64 + mi * 16 + lj * 4 + j;
                float v = acc2[mi][j] + bi;
                v = fmaxf(v, 0.f);
                C[(size_t)r * HID + c] = f2bf(v);
            }
        }
    }
}

// ------------------------------------------------------------------
// Mean aggregation (layer 2), vectorized 16B/lane, bf16 in.
// ------------------------------------------------------------------
template <int F>
__global__ __launch_bounds__(128) void agg_k(
    const ushort* __restrict__ Xh, const int* __restrict__ csr,
    const int* __restrict__ rstart, const int* __restrict__ cnt, int dofs,
    ushort* __restrict__ mean) {
    __shared__ float sh[128][8];
    int d = blockIdx.x;
    int t = threadIdx.x;
    int cg = t & 31, slot = t >> 5;
    int beg = rstart[dofs + d];
    int num = cnt[dofs + d];
    float acc[8] = {};
    for (int e = 0; e < num; e += 8) {
        int i0 = e + slot, i1 = e + 4 + slot;
        bool v0 = i0 < num, v1 = i1 < num;
        int r0 = v0 ? csr[beg + i0] : 0;
        int r1 = v1 ? csr[beg + i1] : 0;
        if (v0) {
            short8 x = *(const short8*)&Xh[(size_t)r0 * F + cg * 8];
#pragma unroll
            for (int i = 0; i < 8; ++i) acc[i] += bf2f((ushort)x[i]);
        }
        if (v1) {
            short8 x = *(const short8*)&Xh[(size_t)r1 * F + cg * 8];
#pragma unroll
            for (int i = 0; i < 8; ++i) acc[i] += bf2f((ushort)x[i]);
        }
    }
#pragma unroll
    for (int i = 0; i < 8; ++i) sh[t][i] = acc[i];
    __syncthreads();
    if (t < 32) {
        float inv = 1.f / (float)((num > 0) ? num : 1);
        short8 ov;
#pragma unroll
        for (int i = 0; i < 8; ++i) {
            float s = sh[t][i] + sh[t + 32][i] + sh[t + 64][i] + sh[t + 96][i];
            ov[i] = (short)f2bf(s * inv);
        }
        *(short8*)&mean[(size_t)d * F + t * 8] = ov;
    }
}

// ------------------------------------------------------------------
// bf16 MFMA concat-K GEMM (layer 2): C = [A0 | A1] @ Bt^T + bias
// ------------------------------------------------------------------
template <int BM, int KHALF, int NCOLS, bool RELU, bool OUT_BF16>
__global__ __launch_bounds__(256) void mgemm_k(
    const ushort* __restrict__ A0, const ushort* __restrict__ A1,
    const ushort* __restrict__ Bt, const float* __restrict__ bias,
    void* __restrict__ Cv, int M) {
    constexpr int MI = BM / 32;
    constexpr int TPR = 256 / BM;
    constexpr int AV = 64 / TPR / 8;
    __shared__ ushort As[BM][72];
    __shared__ ushort Bs[64][72];

    int t = threadIdx.x;
    int row0 = blockIdx.x * BM;
    int col0 = blockIdx.y * 64;
    int lane = t & 63;
    int w = t >> 6, wm = w >> 1, wn = w & 1;
    int lr = lane & 15;
    int lk = (lane >> 4) * 8;

    int ar = t / TPR, ac = (t % TPR) * (64 / TPR);
    int bn = t >> 2, bc = (t & 3) * 16;

    f32x4 acc[MI][2] = {};

    for (int k0 = 0; k0 < 2 * KHALF; k0 += 64) {
        const ushort* Asrc = (k0 < KHALF) ? A0 : A1;
        int kof = (k0 < KHALF) ? k0 : (k0 - KHALF);
        const ushort* ap = &Asrc[(size_t)(row0 + ar) * KHALF + kof + ac];
        const ushort* bp = &Bt[(size_t)(col0 + bn) * (2 * KHALF) + k0 + bc];
        short8 av[AV];
#pragma unroll
        for (int i = 0; i < AV; ++i) av[i] = *(const short8*)(ap + 8 * i);
        short8 bv0 = *(const short8*)(bp);
        short8 bv1 = *(const short8*)(bp + 8);
        __syncthreads();
#pragma unroll
        for (int i = 0; i < AV; ++i) *(short8*)&As[ar][ac + 8 * i] = av[i];
        *(short8*)&Bs[bn][bc + 0] = bv0;
        *(short8*)&Bs[bn][bc + 8] = bv1;
        __syncthreads();
#pragma unroll
        for (int ks = 0; ks < 64; ks += 32) {
            short8 bf0 = *(const short8*)&Bs[wn * 32 + lr][ks + lk];
            short8 bf1 = *(const short8*)&Bs[wn * 32 + 16 + lr][ks + lk];
#pragma unroll
            for (int mi = 0; mi < MI; ++mi) {
                short8 af = *(const short8*)&As[wm * (BM / 2) + mi * 16 + lr][ks + lk];
                acc[mi][0] = __builtin_amdgcn_mfma_f32_16x16x32_bf16(af, bf0, acc[mi][0], 0, 0, 0);
                acc[mi][1] = __builtin_amdgcn_mfma_f32_16x16x32_bf16(af, bf1, acc[mi][1], 0, 0, 0);
            }
        }
    }

    int orow = row0 + wm * (BM / 2);
    int ocol = col0 + wn * 32;
#pragma unroll
    for (int mi = 0; mi < MI; ++mi) {
#pragma unroll
        for (int ni = 0; ni < 2; ++ni) {
            int c = ocol + ni * 16 + lr;
            float bi = bias[c];
#pragma unroll
            for (int j = 0; j < 4; ++j) {
                int r = orow + mi * 16 + (lane >> 4) * 4 + j;
                float v = acc[mi][ni][j] + bi;
                if (RELU) v = fmaxf(v, 0.f);
                if (OUT_BF16)
                    ((ushort*)Cv)[(size_t)r * NCOLS + c] = f2bf(v);
                else
                    ((float*)Cv)[(size_t)r * NCOLS + c] = v;
            }
        }
    }
}

// ------------------------------------------------------------------
extern "C" void kernel_launch(void* const* d_in, const int* in_sizes, int n_in,
                              void* d_out, int out_size, void* d_ws, size_t ws_size,
                              hipStream_t stream) {
    const float* x_all = (const float*)d_in[0];
    const int* n_id = (const int*)d_in[1];
    const int* esrc0 = (const int*)d_in[2];
    const int* edst0 = (const int*)d_in[3];
    const int* esrc1 = (const int*)d_in[4];
    const int* edst1 = (const int*)d_in[5];
    const float* W_l0 = (const float*)d_in[6];
    const float* b_l0 = (const float*)d_in[7];
    const float* W_r0 = (const float*)d_in[8];
    const float* W_l1 = (const float*)d_in[9];
    const float* b_l1 = (const float*)d_in[10];
    const float* W_r1 = (const float*)d_in[11];

    char* ws = (char*)d_ws;
    size_t off = 0;
    auto alloc = [&](size_t bytes) {
        off = (off + 255) & ~(size_t)255;
        void* p = ws + off;
        off += bytes;
        return p;
    };
    int* cntcur = (int*)alloc((size_t)2 * NDT * 4);  // [cnt | cursor], one memset
    int* cnt = cntcur;
    int* cur = cntcur + NDT;
    int* rs = (int*)alloc((size_t)NDT * 4);
    int* csr = (int*)alloc((size_t)NET * 4);
    int* bsum = (int*)alloc(1024 * 4);
    int* boff = (int*)alloc(1024 * 4);
    ushort* h = (ushort*)alloc((size_t)ND0 * HID * 2);
    ushort* mean1 = (ushort*)alloc((size_t)ND1 * HID * 2);
    ushort* Bt0 = (ushort*)alloc((size_t)HID * (2 * F_IN) * 2);
    ushort* Bt1 = (ushort*)alloc((size_t)F_OUT * (2 * HID) * 2);

    hipMemsetAsync(cntcur, 0, (size_t)2 * NDT * 4, stream);

    // weight prep + CSR build (both layers combined)
    wtrans_all_k<<<512, 256, 0, stream>>>(W_l0, W_r0, W_l1, W_r1, Bt0, Bt1);
    hist_all_k<<<NET / 256, 256, 0, stream>>>(edst0, edst1, cnt);
    scan_part_k<<<NDT / 1024, 256, 0, stream>>>(cnt, rs, bsum, NDT);
    scan_part_k<<<1, 256, 0, stream>>>(bsum, boff, nullptr, NDT / 1024);
    scan_add_k<<<NDT / 256, 256, 0, stream>>>(rs, boff, NDT);
    scatter_all_k<<<NET / 256, 256, 0, stream>>>(esrc0, edst0, esrc1, edst1, n_id,
                                                 rs, cur, csr);

    // ---------------- Layer 1 (fused agg + gather + GEMM) ----------------
    fused1_k<<<ND0 / 128, 512, 0, stream>>>(x_all, csr, rs, cnt, n_id, Bt0, b_l0, h);

    // ---------------- Layer 2 ----------------
    agg_k<HID><<<ND1, 128, 0, stream>>>(h, csr, rs, cnt, ND0, mean1);
    mgemm_k<64, HID, F_OUT, false, false>
        <<<dim3(ND1 / 64, F_OUT / 64), 256, 0, stream>>>(mean1, h, Bt1, b_l1,
                                                         (float*)d_out, ND1);
}

// Round 5
// 319.006 us; speedup vs baseline: 1.5392x; 1.0098x over previous
//
#include <hip/hip_runtime.h>

// Problem constants (from setup_inputs)
#define ND0 90112
#define ND1 8192
#define NDT (ND0 + ND1)         // 98304 combined dst space
#define NE0 1351680
#define NE1 81920
#define NET (NE0 + NE1)
#define F_IN 128
#define HID 256
#define F_OUT 128

typedef __attribute__((ext_vector_type(8))) short short8;
typedef __attribute__((ext_vector_type(4))) float f32x4;

__device__ inline ushort f2bf(float f) {
    unsigned u = __float_as_uint(f);
    return (ushort)((u + 0x7fffu + ((u >> 16) & 1u)) >> 16);
}
__device__ inline float bf2f(ushort h) {
    return __uint_as_float(((unsigned)h) << 16);
}

// ------------------------------------------------------------------
// Combined CSR build over [layer0 dsts | layer1 dsts]
// ------------------------------------------------------------------
__global__ void hist_all_k(const int* __restrict__ edst0, const int* __restrict__ edst1,
                           int* __restrict__ cnt) {
    int e = blockIdx.x * 256 + threadIdx.x;
    if (e < NE0)
        atomicAdd(&cnt[edst0[e]], 1);
    else if (e < NET)
        atomicAdd(&cnt[ND0 + edst1[e - NE0]], 1);
}

// 1024-elem chunks: per-chunk exclusive scan + chunk totals
__global__ void scan_part_k(const int* __restrict__ in, int* __restrict__ out,
                            int* __restrict__ bsum, int n) {
    __shared__ int sh[256];
    int base = blockIdx.x * 1024;
    int t = threadIdx.x;
    int v[4];
    int s = 0;
#pragma unroll
    for (int i = 0; i < 4; ++i) {
        int idx = base + t * 4 + i;
        v[i] = (idx < n) ? in[idx] : 0;
        s += v[i];
    }
    sh[t] = s;
    __syncthreads();
    for (int off = 1; off < 256; off <<= 1) {
        int x = (t >= off) ? sh[t - off] : 0;
        __syncthreads();
        sh[t] += x;
        __syncthreads();
    }
    int excl = (t == 0) ? 0 : sh[t - 1];
    if (t == 255 && bsum) bsum[blockIdx.x] = sh[255];
#pragma unroll
    for (int i = 0; i < 4; ++i) {
        int idx = base + t * 4 + i;
        if (idx < n) out[idx] = excl;
        excl += v[i];
    }
}

__global__ void scan_add_k(int* __restrict__ out, const int* __restrict__ boff, int n) {
    int i = blockIdx.x * 256 + threadIdx.x;
    if (i < n) out[i] += boff[i >> 10];
}

// scatter both layers; layer0 src pre-mapped through n_id
__global__ void scatter_all_k(const int* __restrict__ esrc0, const int* __restrict__ edst0,
                              const int* __restrict__ esrc1, const int* __restrict__ edst1,
                              const int* __restrict__ nid, const int* __restrict__ rstart,
                              int* __restrict__ cursor, int* __restrict__ csr) {
    int e = blockIdx.x * 256 + threadIdx.x;
    if (e >= NET) return;
    int d, s;
    if (e < NE0) {
        d = edst0[e];
        s = nid[esrc0[e]];
    } else {
        int e1 = e - NE0;
        d = ND0 + edst1[e1];
        s = esrc1[e1];
    }
    int pos = rstart[d] + atomicAdd(&cursor[d], 1);
    csr[pos] = s;
}

// ------------------------------------------------------------------
// Merged weight transpose+convert for both layers
// ------------------------------------------------------------------
__global__ void wtrans_all_k(const float* __restrict__ Wl0, const float* __restrict__ Wr0,
                             const float* __restrict__ Wl1, const float* __restrict__ Wr1,
                             ushort* __restrict__ Bt0, ushort* __restrict__ Bt1) {
    int idx = blockIdx.x * 256 + threadIdx.x;
    constexpr int N0 = HID * 2 * F_IN;  // 65536
    if (idx < N0) {
        int K2 = 2 * F_IN;
        int n = idx / K2, k = idx - n * K2;
        float v = (k < F_IN) ? Wl0[(size_t)k * HID + n] : Wr0[(size_t)(k - F_IN) * HID + n];
        Bt0[idx] = f2bf(v);
    } else {
        int j = idx - N0;  // F_OUT * 2 * HID = 65536
        int K2 = 2 * HID;
        int n = j / K2, k = j - n * K2;
        float v = (k < HID) ? Wl1[(size_t)k * F_OUT + n] : Wr1[(size_t)(k - HID) * F_OUT + n];
        Bt1[j] = f2bf(v);
    }
}

// ------------------------------------------------------------------
// FUSED layer-1: aggregate (mean) + x_dst gather -> LDS A-tile -> MFMA GEMM
//   h[128 rows][256] = relu([mean | x_dst] @ Bt0^T + bias)
// 704 blocks x 512 threads (8 waves). LDS: As 128x264 bf16 (67.6 KB) + Bs 9.2 KB.
// Phase 1: 4 passes of 32 rows; per row 4 edge-slots x 4 col-chunks,
// slot partials combined via __shfl_xor (slots = lane bits 2..3).
// ------------------------------------------------------------------
__global__ __launch_bounds__(512, 4) void fused1_k(
    const float* __restrict__ X, const int* __restrict__ csr,
    const int* __restrict__ rstart, const int* __restrict__ cnt,
    const int* __restrict__ nid, const ushort* __restrict__ Bt,
    const float* __restrict__ bias, ushort* __restrict__ C) {
    __shared__ ushort As[128][264];  // [row][mean(0..127) | xdst(128..255)], +8 pad
    __shared__ ushort Bs[64][72];
    __shared__ int s_beg[128], s_num[128];

    int t = threadIdx.x;
    int row0 = blockIdx.x * 128;

    if (t < 128) {
        s_beg[t] = rstart[row0 + t];
        s_num[t] = cnt[row0 + t];
    }
    __syncthreads();

    // ---------- phase 1a: x_dst gather (row = t>>2, 32 cols per thread) ----------
    {
        int row = t >> 2, q = t & 3;
        int gr = nid[row0 + row];
        const float* gp = &X[(size_t)gr * F_IN + q * 32];
#pragma unroll
        for (int i = 0; i < 4; ++i) {
            float4 v0 = *(const float4*)(gp + i * 8);
            float4 v1 = *(const float4*)(gp + i * 8 + 4);
            short8 o;
            o[0] = (short)f2bf(v0.x); o[1] = (short)f2bf(v0.y);
            o[2] = (short)f2bf(v0.z); o[3] = (short)f2bf(v0.w);
            o[4] = (short)f2bf(v1.x); o[5] = (short)f2bf(v1.y);
            o[6] = (short)f2bf(v1.z); o[7] = (short)f2bf(v1.w);
            *(short8*)&As[row][F_IN + q * 32 + i * 8] = o;
        }
    }

    // ---------- phase 1b: edge aggregation, 4 passes of 32 rows ----------
    {
        int q = t & 3;             // col chunk (32 floats)
        int slot = (t >> 2) & 3;   // edge slot (lane bits 2..3)
        int rloc = t >> 4;         // row within pass [0,32)
#pragma unroll 1
        for (int pass = 0; pass < 4; ++pass) {
            int row = pass * 32 + rloc;
            int beg = s_beg[row], num = s_num[row];
            float acc[32] = {};
#pragma unroll 1
            for (int e = slot; e < num; e += 4) {
                int r = csr[beg + e];
                const float* rp = &X[(size_t)r * F_IN + q * 32];
#pragma unroll
                for (int i = 0; i < 8; ++i) {
                    float4 v = *(const float4*)(rp + i * 4);
                    acc[i * 4 + 0] += v.x;
                    acc[i * 4 + 1] += v.y;
                    acc[i * 4 + 2] += v.z;
                    acc[i * 4 + 3] += v.w;
                }
            }
            // combine the 4 slots (lane bits 2..3) via butterfly
#pragma unroll
            for (int i = 0; i < 32; ++i) {
                acc[i] += __shfl_xor(acc[i], 4);
                acc[i] += __shfl_xor(acc[i], 8);
            }
            if (slot == 0) {
                float inv = 1.f / (float)((num > 0) ? num : 1);
#pragma unroll
                for (int i = 0; i < 4; ++i) {
                    short8 o;
#pragma unroll
                    for (int j = 0; j < 8; ++j) o[j] = (short)f2bf(acc[i * 8 + j] * inv);
                    *(short8*)&As[row][q * 32 + i * 8] = o;
                }
            }
        }
    }

    // ---------- phase 2: GEMM ----------
    int lane = t & 63;
    int w = t >> 6;
    int wm = w >> 2, wn2 = w & 3;  // 2(m) x 4(n) wave grid; wave tile 64m x 16n
    int lr = lane & 15, lj = lane >> 4;
    int bn = t >> 3, bk = (t & 7) * 8;  // B stage map: 64 n-rows x 64 k

    for (int nt = 0; nt < 4; ++nt) {
        f32x4 acc2[4] = {};
        for (int k0 = 0; k0 < 256; k0 += 64) {
            short8 bv = *(const short8*)&Bt[(size_t)(nt * 64 + bn) * 256 + k0 + bk];
            __syncthreads();  // As writes done (1st iter); prior Bs reads done
            *(short8*)&Bs[bn][bk] = bv;
            __syncthreads();
#pragma unroll
            for (int ks = 0; ks < 64; ks += 32) {
                short8 bf = *(const short8*)&Bs[wn2 * 16 + lr][ks + lj * 8];
#pragma unroll
                for (int mi = 0; mi < 4; ++mi) {
                    short8 af = *(const short8*)&As[wm * 64 + mi * 16 + lr][k0 + ks + lj * 8];
                    acc2[mi] = __builtin_amdgcn_mfma_f32_16x16x32_bf16(af, bf, acc2[mi], 0, 0, 0);
                }
            }
        }
        int c = nt * 64 + wn2 * 16 + lr;
        float bi = bias[c];
#pragma unroll
        for (int mi = 0; mi < 4; ++mi) {
#pragma unroll
            for (int j = 0; j < 4; ++j) {
                int r = row0 + wm * 64 + mi * 16 + lj * 4 + j;
                float v = acc2[mi][j] + bi;
                v = fmaxf(v, 0.f);
                C[(size_t)r * HID + c] = f2bf(v);
            }
        }
    }
}

// ------------------------------------------------------------------
// Mean aggregation (layer 2), vectorized 16B/lane, bf16 in.
// ------------------------------------------------------------------
template <int F>
__global__ __launch_bounds__(128) void agg_k(
    const ushort* __restrict__ Xh, const int* __restrict__ csr,
    const int* __restrict__ rstart, const int* __restrict__ cnt, int dofs,
    ushort* __restrict__ mean) {
    __shared__ float sh[128][8];
    int d = blockIdx.x;
    int t = threadIdx.x;
    int cg = t & 31, slot = t >> 5;
    int beg = rstart[dofs + d];
    int num = cnt[dofs + d];
    float acc[8] = {};
    for (int e = 0; e < num; e += 8) {
        int i0 = e + slot, i1 = e + 4 + slot;
        bool v0 = i0 < num, v1 = i1 < num;
        int r0 = v0 ? csr[beg + i0] : 0;
        int r1 = v1 ? csr[beg + i1] : 0;
        if (v0) {
            short8 x = *(const short8*)&Xh[(size_t)r0 * F + cg * 8];
#pragma unroll
            for (int i = 0; i < 8; ++i) acc[i] += bf2f((ushort)x[i]);
        }
        if (v1) {
            short8 x = *(const short8*)&Xh[(size_t)r1 * F + cg * 8];
#pragma unroll
            for (int i = 0; i < 8; ++i) acc[i] += bf2f((ushort)x[i]);
        }
    }
#pragma unroll
    for (int i = 0; i < 8; ++i) sh[t][i] = acc[i];
    __syncthreads();
    if (t < 32) {
        float inv = 1.f / (float)((num > 0) ? num : 1);
        short8 ov;
#pragma unroll
        for (int i = 0; i < 8; ++i) {
            float s = sh[t][i] + sh[t + 32][i] + sh[t + 64][i] + sh[t + 96][i];
            ov[i] = (short)f2bf(s * inv);
        }
        *(short8*)&mean[(size_t)d * F + t * 8] = ov;
    }
}

// ------------------------------------------------------------------
// bf16 MFMA concat-K GEMM (layer 2): C = [A0 | A1] @ Bt^T + bias
// ------------------------------------------------------------------
template <int BM, int KHALF, int NCOLS, bool RELU, bool OUT_BF16>
__global__ __launch_bounds__(256) void mgemm_k(
    const ushort* __restrict__ A0, const ushort* __restrict__ A1,
    const ushort* __restrict__ Bt, const float* __restrict__ bias,
    void* __restrict__ Cv, int M) {
    constexpr int MI = BM / 32;
    constexpr int TPR = 256 / BM;
    constexpr int AV = 64 / TPR / 8;
    __shared__ ushort As[BM][72];
    __shared__ ushort Bs[64][72];

    int t = threadIdx.x;
    int row0 = blockIdx.x * BM;
    int col0 = blockIdx.y * 64;
    int lane = t & 63;
    int w = t >> 6, wm = w >> 1, wn = w & 1;
    int lr = lane & 15;
    int lk = (lane >> 4) * 8;

    int ar = t / TPR, ac = (t % TPR) * (64 / TPR);
    int bn = t >> 2, bc = (t & 3) * 16;

    f32x4 acc[MI][2] = {};

    for (int k0 = 0; k0 < 2 * KHALF; k0 += 64) {
        const ushort* Asrc = (k0 < KHALF) ? A0 : A1;
        int kof = (k0 < KHALF) ? k0 : (k0 - KHALF);
        const ushort* ap = &Asrc[(size_t)(row0 + ar) * KHALF + kof + ac];
        const ushort* bp = &Bt[(size_t)(col0 + bn) * (2 * KHALF) + k0 + bc];
        short8 av[AV];
#pragma unroll
        for (int i = 0; i < AV; ++i) av[i] = *(const short8*)(ap + 8 * i);
        short8 bv0 = *(const short8*)(bp);
        short8 bv1 = *(const short8*)(bp + 8);
        __syncthreads();
#pragma unroll
        for (int i = 0; i < AV; ++i) *(short8*)&As[ar][ac + 8 * i] = av[i];
        *(short8*)&Bs[bn][bc + 0] = bv0;
        *(short8*)&Bs[bn][bc + 8] = bv1;
        __syncthreads();
#pragma unroll
        for (int ks = 0; ks < 64; ks += 32) {
            short8 bf0 = *(const short8*)&Bs[wn * 32 + lr][ks + lk];
            short8 bf1 = *(const short8*)&Bs[wn * 32 + 16 + lr][ks + lk];
#pragma unroll
            for (int mi = 0; mi < MI; ++mi) {
                short8 af = *(const short8*)&As[wm * (BM / 2) + mi * 16 + lr][ks + lk];
                acc[mi][0] = __builtin_amdgcn_mfma_f32_16x16x32_bf16(af, bf0, acc[mi][0], 0, 0, 0);
                acc[mi][1] = __builtin_amdgcn_mfma_f32_16x16x32_bf16(af, bf1, acc[mi][1], 0, 0, 0);
            }
        }
    }

    int orow = row0 + wm * (BM / 2);
    int ocol = col0 + wn * 32;
#pragma unroll
    for (int mi = 0; mi < MI; ++mi) {
#pragma unroll
        for (int ni = 0; ni < 2; ++ni) {
            int c = ocol + ni * 16 + lr;
            float bi = bias[c];
#pragma unroll
            for (int j = 0; j < 4; ++j) {
                int r = orow + mi * 16 + (lane >> 4) * 4 + j;
                float v = acc[mi][ni][j] + bi;
                if (RELU) v = fmaxf(v, 0.f);
                if (OUT_BF16)
                    ((ushort*)Cv)[(size_t)r * NCOLS + c] = f2bf(v);
                else
                    ((float*)Cv)[(size_t)r * NCOLS + c] = v;
            }
        }
    }
}

// ------------------------------------------------------------------
extern "C" void kernel_launch(void* const* d_in, const int* in_sizes, int n_in,
                              void* d_out, int out_size, void* d_ws, size_t ws_size,
                              hipStream_t stream) {
    const float* x_all = (const float*)d_in[0];
    const int* n_id = (const int*)d_in[1];
    const int* esrc0 = (const int*)d_in[2];
    const int* edst0 = (const int*)d_in[3];
    const int* esrc1 = (const int*)d_in[4];
    const int* edst1 = (const int*)d_in[5];
    const float* W_l0 = (const float*)d_in[6];
    const float* b_l0 = (const float*)d_in[7];
    const float* W_r0 = (const float*)d_in[8];
    const float* W_l1 = (const float*)d_in[9];
    const float* b_l1 = (const float*)d_in[10];
    const float* W_r1 = (const float*)d_in[11];

    char* ws = (char*)d_ws;
    size_t off = 0;
    auto alloc = [&](size_t bytes) {
        off = (off + 255) & ~(size_t)255;
        void* p = ws + off;
        off += bytes;
        return p;
    };
    int* cntcur = (int*)alloc((size_t)2 * NDT * 4);  // [cnt | cursor], one memset
    int* cnt = cntcur;
    int* cur = cntcur + NDT;
    int* rs = (int*)alloc((size_t)NDT * 4);
    int* csr = (int*)alloc((size_t)NET * 4);
    int* bsum = (int*)alloc(1024 * 4);
    int* boff = (int*)alloc(1024 * 4);
    ushort* h = (ushort*)alloc((size_t)ND0 * HID * 2);
    ushort* mean1 = (ushort*)alloc((size_t)ND1 * HID * 2);
    ushort* Bt0 = (ushort*)alloc((size_t)HID * (2 * F_IN) * 2);
    ushort* Bt1 = (ushort*)alloc((size_t)F_OUT * (2 * HID) * 2);

    hipMemsetAsync(cntcur, 0, (size_t)2 * NDT * 4, stream);

    // weight prep + CSR build (both layers combined)
    wtrans_all_k<<<512, 256, 0, stream>>>(W_l0, W_r0, W_l1, W_r1, Bt0, Bt1);
    hist_all_k<<<NET / 256, 256, 0, stream>>>(edst0, edst1, cnt);
    scan_part_k<<<NDT / 1024, 256, 0, stream>>>(cnt, rs, bsum, NDT);
    scan_part_k<<<1, 256, 0, stream>>>(bsum, boff, nullptr, NDT / 1024);
    scan_add_k<<<NDT / 256, 256, 0, stream>>>(rs, boff, NDT);
    scatter_all_k<<<NET / 256, 256, 0, stream>>>(esrc0, edst0, esrc1, edst1, n_id,
                                                 rs, cur, csr);

    // ---------------- Layer 1 (fused agg + gather + GEMM) ----------------
    fused1_k<<<ND0 / 128, 512, 0, stream>>>(x_all, csr, rs, cnt, n_id, Bt0, b_l0, h);

    // ---------------- Layer 2 ----------------
    agg_k<HID><<<ND1, 128, 0, stream>>>(h, csr, rs, cnt, ND0, mean1);
    mgemm_k<64, HID, F_OUT, false, false>
        <<<dim3(ND1 / 64, F_OUT / 64), 256, 0, stream>>>(mean1, h, Bt1, b_l1,
                                                         (float*)d_out, ND1);
}